// Round 1
// baseline (520.681 us; speedup 1.0000x reference)
//
#include <hip/hip_runtime.h>

#define T_DIM 16384
#define H_DIM 2048
#define I_DIM 1408
#define NB_DIM (2 * I_DIM)   // 2816 interleaved gate/up columns

typedef _Float16 half8 __attribute__((ext_vector_type(8)));
typedef float floatx4 __attribute__((ext_vector_type(4)));

// -------- async global -> LDS, 16 bytes per lane (gfx950) --------
__device__ __forceinline__ void async_cp16(const _Float16* gp, _Float16* lp) {
    __builtin_amdgcn_global_load_lds(
        (const __attribute__((address_space(1))) unsigned int*)gp,
        (__attribute__((address_space(3))) unsigned int*)lp,
        16, 0, 0);
}

// -------- fp32 -> fp16 conversion of x --------
__global__ void cvt_fp16_kernel(const float* __restrict__ x, _Float16* __restrict__ xh) {
    int i = (blockIdx.x * 256 + threadIdx.x) * 8;
    const float4* p = (const float4*)(x + i);
    float4 a = p[0];
    float4 b = p[1];
    half8 o = { (_Float16)a.x, (_Float16)a.y, (_Float16)a.z, (_Float16)a.w,
                (_Float16)b.x, (_Float16)b.y, (_Float16)b.z, (_Float16)b.w };
    *(half8*)(xh + i) = o;
}

// -------- GPTQ dequant -> transposed fp16 weight Wt[n'][k] (unchanged, verified) --------
__global__ void dequant_kernel(const int* __restrict__ qw, const int* __restrict__ qz,
                               const float* __restrict__ sc, _Float16* __restrict__ Wt,
                               int K, int N, int interleave, int off) {
    __shared__ half8 tile[256];
    int t = threadIdx.x;
    int nl = t & 63, kl = t >> 6;
    int n  = blockIdx.x * 64 + nl;
    int kp = blockIdx.y * 4 + kl;
    int q = qw[kp * N + n];
    int g = kp >> 4;
    float scale = sc[g * N + n];
    int zq = (qz[g * (N >> 3) + (n >> 3)] >> (4 * (n & 7))) & 0xF;
    float zf = (float)(zq + 1);
    half8 o;
#pragma unroll
    for (int j = 0; j < 8; ++j)
        o[j] = (_Float16)(((float)((q >> (4 * j)) & 0xF) - zf) * scale);
    tile[nl * 4 + kl] = o;
    __syncthreads();
    int nl2 = t >> 2, kl2 = t & 3;
    int n2 = blockIdx.x * 64 + nl2;
    int np = interleave ? (((n2 >> 5) << 6) + (n2 & 31) + off) : n2;
    *(half8*)(Wt + (size_t)np * K + (size_t)(blockIdx.y * 4 + kl2) * 8) = tile[nl2 * 4 + kl2];
}

// ============ 256x256 8-phase GEMM (T2+T3+T4+T5), BK=64, 512 threads, 128 KiB LDS ============
// Per tile t (parity p), quadrant order per wave: (mh,nh) = (0,0),(0,1),(1,0),(1,1).
// Tile-half read schedule: A-half h last ds_read at ph2 (by wm==h waves);
//                          B-half h last ds_read at ph1 (by wn>>1==h waves).
// Stage slots (one 128x64 half-tile = 2 global_load_lds per wave per slot):
//   ph0: A1(t+1)->bufA[p^1]h1   ph1: B1(t+1)->bufB[p^1]h1
//   ph2: B0(t+2)->bufB[p]h0 (after B-half0 release)   ph3: A0(t+2)->bufA[p]h0 (after A-half0 release)
// Steady-state wait: vmcnt(4) at tile start (newest 2 half-tiles = B0(t+1),A0(t+1) may stay in flight).
// Prologue issue order must match stream: B0(0),A0(0),A1(0),B1(0),B0(1),A0(1).
// LDS swizzle: chunk c of row r stored at c^(r&7) (measured 0 bank conflicts in prior rounds).

#define STAGE_A(p, h, kt) do {                                                        \
    async_cp16(ag + (size_t)((h) * 128) * KDIM + (size_t)(kt) * 64,                   \
               &As[p][(h) * 8192 + ldst]);                                            \
    async_cp16(ag + (size_t)((h) * 128 + 64) * KDIM + (size_t)(kt) * 64,              \
               &As[p][(h) * 8192 + 4096 + ldst]);                                     \
} while (0)

#define STAGE_B(p, h, kt) do {                                                        \
    async_cp16(bg + (size_t)((h) * 128) * KDIM + (size_t)(kt) * 64,                   \
               &Bs[p][(h) * 8192 + ldst]);                                            \
    async_cp16(bg + (size_t)((h) * 128 + 64) * KDIM + (size_t)(kt) * 64,              \
               &Bs[p][(h) * 8192 + 4096 + ldst]);                                     \
} while (0)

#define PHASE(p, mh, nh, RA, RB, ...) do {                                            \
    if (RA) {                                                                         \
        _Pragma("unroll") for (int i_ = 0; i_ < 4; ++i_)                              \
        _Pragma("unroll") for (int kk_ = 0; kk_ < 2; ++kk_)                           \
            af[i_][kk_] = *(const half8*)&As[p][(mh) * 4096 + (aoff[i_] ^ (kk_ * 32))]; \
    }                                                                                 \
    if (RB) {                                                                         \
        _Pragma("unroll") for (int j_ = 0; j_ < 2; ++j_)                              \
        _Pragma("unroll") for (int kk_ = 0; kk_ < 2; ++kk_)                           \
            bf[nh][j_][kk_] = *(const half8*)&Bs[p][(nh) * 2048 + (boff[j_] ^ (kk_ * 32))]; \
    }                                                                                 \
    __VA_ARGS__;                                                                      \
    asm volatile("s_barrier" ::: "memory");                                           \
    __builtin_amdgcn_s_setprio(1);                                                    \
    _Pragma("unroll") for (int kk_ = 0; kk_ < 2; ++kk_)                               \
    _Pragma("unroll") for (int i_ = 0; i_ < 4; ++i_)                                  \
    _Pragma("unroll") for (int j_ = 0; j_ < 2; ++j_)                                  \
        acc[(mh) * 4 + i_][(nh) * 2 + j_] = __builtin_amdgcn_mfma_f32_16x16x32_f16(   \
            af[i_][kk_], bf[nh][j_][kk_], acc[(mh) * 4 + i_][(nh) * 2 + j_], 0, 0, 0);\
    __builtin_amdgcn_s_setprio(0);                                                    \
    asm volatile("s_barrier" ::: "memory");                                           \
} while (0)

#define TILE(p, kt) do {                                                              \
    asm volatile("s_waitcnt vmcnt(4)" ::: "memory");                                  \
    asm volatile("s_barrier" ::: "memory");                                           \
    PHASE(p, 0, 0, 1, 1, if ((kt) + 1 < NT) STAGE_A(p ^ 1, 1, (kt) + 1));             \
    PHASE(p, 0, 1, 0, 1, if ((kt) + 1 < NT) STAGE_B(p ^ 1, 1, (kt) + 1));             \
    PHASE(p, 1, 0, 1, 0, if ((kt) + 2 < NT) STAGE_B(p, 0, (kt) + 2));                 \
    PHASE(p, 1, 1, 0, 0, if ((kt) + 2 < NT) STAGE_A(p, 0, (kt) + 2));                 \
} while (0)

template<int KDIM, int EPI>
__launch_bounds__(512, 2)
__global__ void gemm256(const _Float16* __restrict__ A,
                        const _Float16* __restrict__ B,
                        void* __restrict__ Cout) {
    constexpr int NT = KDIM / 64;                 // 32 (gemm1) / 22 (gemm2), both even, >= 4
    __shared__ __align__(16) _Float16 As[2][16384];   // [buf][256 rows * 64 halves]
    __shared__ __align__(16) _Float16 Bs[2][16384];

    const int t = threadIdx.x;
    const int wave = t >> 6, lane = t & 63;
    const int id = blockIdx.x;
    const int m0 = (id & 63) * 256;               // 64 m-panels exactly; m fastest (A L3-window)
    const int n_p = id >> 6;
    const int n0 = n_p * 256;
    const int wm = wave >> 2, wn = wave & 3;      // 2x4 wave grid; wave tile 128(M) x 64(N)
    const int q4 = lane >> 4, l15 = lane & 15;

    // staging: per-lane global source (pre-swizzled chunk), wave-uniform LDS dest
    const int srow = wave * 8 + (lane >> 3);
    const int schunk = (lane & 7) ^ (lane >> 3);
    const _Float16* ag = A + (size_t)(m0 + srow) * KDIM + schunk * 8;
    const _Float16* bg = B + (size_t)(n0 + srow) * KDIM + schunk * 8;
    const int ldst = wave * 512;                  // halves

    int aoff[4], boff[2];
#pragma unroll
    for (int i = 0; i < 4; ++i) {
        int rA = wm * 128 + i * 16 + l15;
        aoff[i] = rA * 64 + ((q4 ^ (rA & 7)) * 8);
    }
#pragma unroll
    for (int j = 0; j < 2; ++j) {
        int rB = wn * 64 + j * 16 + l15;
        boff[j] = rB * 64 + ((q4 ^ (rB & 7)) * 8);
    }

    floatx4 zero = {0.f, 0.f, 0.f, 0.f};
    floatx4 acc[8][4];
#pragma unroll
    for (int mi = 0; mi < 8; ++mi)
#pragma unroll
        for (int ni = 0; ni < 4; ++ni) acc[mi][ni] = zero;

    half8 af[4][2];        // current A quadrant frags (reused across 2 phases)
    half8 bf[2][2][2];     // [nh][frag][kk] — both B halves kept live

    // prologue: B0(0), A0(0), A1(0), B1(0), B0(1), A0(1)  (12 issues/wave)
    STAGE_B(0, 0, 0);
    STAGE_A(0, 0, 0);
    STAGE_A(0, 1, 0);
    STAGE_B(0, 1, 0);
    STAGE_B(1, 0, 1);
    STAGE_A(1, 0, 1);

    for (int tt = 0; tt < NT; tt += 2) {
        TILE(0, tt);
        TILE(1, tt + 1);
    }

    if constexpr (EPI == 1) {
        // ni 0,1 = gate, ni 2,3 = up of the same h-columns (wave covers one full 64-col group)
        _Float16* hout = (_Float16*)Cout;
        const int rbase = m0 + wm * 128 + q4 * 4;
        const int colbase = (n_p * 4 + wn) * 32 + l15;
#pragma unroll
        for (int mi = 0; mi < 8; ++mi)
#pragma unroll
            for (int nc = 0; nc < 2; ++nc)
#pragma unroll
                for (int r = 0; r < 4; ++r) {
                    int row = rbase + mi * 16 + r;
                    int col = colbase + nc * 16;
                    float g = acc[mi][nc][r];
                    float u = acc[mi][nc + 2][r];
                    float s = (g / (1.0f + __expf(-g))) * u;
                    hout[(size_t)row * I_DIM + col] = (_Float16)s;
                }
    } else {
        float* outp = (float*)Cout;
        const int rbase = m0 + wm * 128 + q4 * 4;
#pragma unroll
        for (int mi = 0; mi < 8; ++mi)
#pragma unroll
            for (int ni = 0; ni < 4; ++ni)
#pragma unroll
                for (int r = 0; r < 4; ++r) {
                    int row = rbase + mi * 16 + r;
                    int col = n0 + wn * 64 + ni * 16 + l15;
                    outp[(size_t)row * H_DIM + col] = acc[mi][ni][r];
                }
    }
}

extern "C" void kernel_launch(void* const* d_in, const int* in_sizes, int n_in,
                              void* d_out, int out_size, void* d_ws, size_t ws_size,
                              hipStream_t stream) {
    const float* x    = (const float*)d_in[0];
    const int* qw_g   = (const int*)d_in[1];
    const int* qz_g   = (const int*)d_in[2];
    const float* sc_g = (const float*)d_in[3];
    const int* qw_u   = (const int*)d_in[4];
    const int* qz_u   = (const int*)d_in[5];
    const float* sc_u = (const float*)d_in[6];
    const int* qw_d   = (const int*)d_in[7];
    const int* qz_d   = (const int*)d_in[8];
    const float* sc_d = (const float*)d_in[9];
    float* out = (float*)d_out;

    // ws (fp16): xh 64MiB | h 44MiB | B' 11MiB | Wd_t 5.5MiB
    char* ws = (char*)d_ws;
    _Float16* xh  = (_Float16*)ws;  ws += (size_t)T_DIM * H_DIM * sizeof(_Float16);
    _Float16* hh  = (_Float16*)ws;  ws += (size_t)T_DIM * I_DIM * sizeof(_Float16);
    _Float16* Bgu = (_Float16*)ws;  ws += (size_t)NB_DIM * H_DIM * sizeof(_Float16);
    _Float16* Wd  = (_Float16*)ws;  ws += (size_t)I_DIM * H_DIM * sizeof(_Float16);

    cvt_fp16_kernel<<<(T_DIM * H_DIM) / 2048, 256, 0, stream>>>(x, xh);
    dequant_kernel<<<dim3(I_DIM / 64, H_DIM / 32), 256, 0, stream>>>(qw_g, qz_g, sc_g, Bgu, H_DIM, I_DIM, 1, 0);
    dequant_kernel<<<dim3(I_DIM / 64, H_DIM / 32), 256, 0, stream>>>(qw_u, qz_u, sc_u, Bgu, H_DIM, I_DIM, 1, 32);
    dequant_kernel<<<dim3(H_DIM / 64, I_DIM / 32), 256, 0, stream>>>(qw_d, qz_d, sc_d, Wd, I_DIM, H_DIM, 0, 0);
    gemm256<H_DIM, 1><<<(T_DIM / 256) * (NB_DIM / 256), 512, 0, stream>>>(xh, Bgu, hh);
    gemm256<I_DIM, 0><<<(T_DIM / 256) * (H_DIM / 256), 512, 0, stream>>>(hh, Wd, out);
}

// Round 2
// 497.765 us; speedup vs baseline: 1.0460x; 1.0460x over previous
//
#include <hip/hip_runtime.h>

#define T_DIM 16384
#define H_DIM 2048
#define I_DIM 1408
#define NB_DIM (2 * I_DIM)   // 2816 interleaved gate/up columns

typedef _Float16 half8 __attribute__((ext_vector_type(8)));
typedef float floatx4 __attribute__((ext_vector_type(4)));

// -------- async global -> LDS, 16 bytes per lane (gfx950) --------
__device__ __forceinline__ void async_cp16(const _Float16* gp, _Float16* lp) {
    __builtin_amdgcn_global_load_lds(
        (const __attribute__((address_space(1))) unsigned int*)gp,
        (__attribute__((address_space(3))) unsigned int*)lp,
        16, 0, 0);
}

// -------- fp32 -> fp16 conversion of x --------
__global__ void cvt_fp16_kernel(const float* __restrict__ x, _Float16* __restrict__ xh) {
    int i = (blockIdx.x * 256 + threadIdx.x) * 8;
    const float4* p = (const float4*)(x + i);
    float4 a = p[0];
    float4 b = p[1];
    half8 o = { (_Float16)a.x, (_Float16)a.y, (_Float16)a.z, (_Float16)a.w,
                (_Float16)b.x, (_Float16)b.y, (_Float16)b.z, (_Float16)b.w };
    *(half8*)(xh + i) = o;
}

// -------- GPTQ dequant -> transposed fp16 weight Wt[n'][k] (unchanged, verified) --------
__global__ void dequant_kernel(const int* __restrict__ qw, const int* __restrict__ qz,
                               const float* __restrict__ sc, _Float16* __restrict__ Wt,
                               int K, int N, int interleave, int off) {
    __shared__ half8 tile[256];
    int t = threadIdx.x;
    int nl = t & 63, kl = t >> 6;
    int n  = blockIdx.x * 64 + nl;
    int kp = blockIdx.y * 4 + kl;
    int q = qw[kp * N + n];
    int g = kp >> 4;
    float scale = sc[g * N + n];
    int zq = (qz[g * (N >> 3) + (n >> 3)] >> (4 * (n & 7))) & 0xF;
    float zf = (float)(zq + 1);
    half8 o;
#pragma unroll
    for (int j = 0; j < 8; ++j)
        o[j] = (_Float16)(((float)((q >> (4 * j)) & 0xF) - zf) * scale);
    tile[nl * 4 + kl] = o;
    __syncthreads();
    int nl2 = t >> 2, kl2 = t & 3;
    int n2 = blockIdx.x * 64 + nl2;
    int np = interleave ? (((n2 >> 5) << 6) + (n2 & 31) + off) : n2;
    *(half8*)(Wt + (size_t)np * K + (size_t)(blockIdx.y * 4 + kl2) * 8) = tile[nl2 * 4 + kl2];
}

// ============ 256x256 8-phase GEMM, BK=64, 512 threads, 128 KiB LDS ============
// Quadrant phases per K-tile t (parity p): (mh,nh) = (0,0),(0,1),(1,0),(1,1).
// Stage slots: ph0: A1(t+1)  ph1: B1(t+1)  ph2: B0(t+2)  ph3: A0(t+2).
// Issue stream: ..., B0(t),A0(t),A1(t),B1(t),B0(t+1),A0(t+1), ...
// Counted waits placed AFTER the MFMA cluster, BEFORE the phase end-barrier
// (barrier publishes cross-wave completion of the cooperatively-written halves):
//   ph0 end: vmcnt(6)  -> drains A1(t),B1(t)   (read in ph1/ph2)
//   ph3 end: vmcnt(8)  -> drains B0(t+1),A0(t+1) (read next tile ph0)
// Steady state: 8 outstanding entering ph0, peak 12; each wait drains exactly 4.
// Last two K-tiles are peeled with waits (6,4) and (0,-) so the hot loop has no branches.
// LDS swizzle: chunk c of row r stored at c^(r&7) (measured 0 bank conflicts).

#define STAGE_A(p, h, kt) do {                                                        \
    async_cp16(ag + (size_t)((h) * 128) * KDIM + (size_t)(kt) * 64,                   \
               &As[p][(h) * 8192 + ldst]);                                            \
    async_cp16(ag + (size_t)((h) * 128 + 64) * KDIM + (size_t)(kt) * 64,              \
               &As[p][(h) * 8192 + 4096 + ldst]);                                     \
} while (0)

#define STAGE_B(p, h, kt) do {                                                        \
    async_cp16(bg + (size_t)((h) * 128) * KDIM + (size_t)(kt) * 64,                   \
               &Bs[p][(h) * 8192 + ldst]);                                            \
    async_cp16(bg + (size_t)((h) * 128 + 64) * KDIM + (size_t)(kt) * 64,              \
               &Bs[p][(h) * 8192 + 4096 + ldst]);                                     \
} while (0)

// PHASE(parity, mh, nh, read-A?, read-B?, stage-stmt, post-MFMA-wait-stmt)
#define PHASE(p, mh, nh, RA, RB, STAGE_STMT, WAIT_STMT) do {                          \
    if (RA) {                                                                         \
        _Pragma("unroll") for (int i_ = 0; i_ < 4; ++i_)                              \
        _Pragma("unroll") for (int kk_ = 0; kk_ < 2; ++kk_)                           \
            af[i_][kk_] = *(const half8*)&As[p][(mh) * 4096 + (aoff[i_] ^ (kk_ * 32))]; \
    }                                                                                 \
    if (RB) {                                                                         \
        _Pragma("unroll") for (int j_ = 0; j_ < 2; ++j_)                              \
        _Pragma("unroll") for (int kk_ = 0; kk_ < 2; ++kk_)                           \
            bf[nh][j_][kk_] = *(const half8*)&Bs[p][(nh) * 2048 + (boff[j_] ^ (kk_ * 32))]; \
    }                                                                                 \
    STAGE_STMT;                                                                       \
    __builtin_amdgcn_s_barrier();                                                     \
    asm volatile("s_waitcnt lgkmcnt(0)" ::: "memory");                                \
    __builtin_amdgcn_s_setprio(1);                                                    \
    _Pragma("unroll") for (int kk_ = 0; kk_ < 2; ++kk_)                               \
    _Pragma("unroll") for (int i_ = 0; i_ < 4; ++i_)                                  \
    _Pragma("unroll") for (int j_ = 0; j_ < 2; ++j_)                                  \
        acc[(mh) * 4 + i_][(nh) * 2 + j_] = __builtin_amdgcn_mfma_f32_16x16x32_f16(   \
            af[i_][kk_], bf[nh][j_][kk_], acc[(mh) * 4 + i_][(nh) * 2 + j_], 0, 0, 0);\
    __builtin_amdgcn_s_setprio(0);                                                    \
    WAIT_STMT;                                                                        \
    __builtin_amdgcn_s_barrier();                                                     \
} while (0)

#define VM(n) asm volatile("s_waitcnt vmcnt(" #n ")" ::: "memory")

// steady-state tile: full stages, waits (6, 8)
#define TILE_FULL(p, kt) do {                                                         \
    PHASE(p, 0, 0, 1, 1, STAGE_A(p ^ 1, 1, (kt) + 1), VM(6));                         \
    PHASE(p, 0, 1, 0, 1, STAGE_B(p ^ 1, 1, (kt) + 1), );                              \
    PHASE(p, 1, 0, 1, 0, STAGE_B(p, 0, (kt) + 2), );                                  \
    PHASE(p, 1, 1, 0, 0, STAGE_A(p, 0, (kt) + 2), VM(8));                             \
} while (0)

// penultimate tile (parity 0, kt = NT-2): stages only t+1 halves, waits (6, 4)
#define TILE_PEN(kt) do {                                                             \
    PHASE(0, 0, 0, 1, 1, STAGE_A(1, 1, (kt) + 1), VM(6));                             \
    PHASE(0, 0, 1, 0, 1, STAGE_B(1, 1, (kt) + 1), );                                  \
    PHASE(0, 1, 0, 1, 0, , );                                                         \
    PHASE(0, 1, 1, 0, 0, , VM(4));                                                    \
} while (0)

// last tile (parity 1): no stages, wait (0, -)
#define TILE_LAST() do {                                                              \
    PHASE(1, 0, 0, 1, 1, , VM(0));                                                    \
    PHASE(1, 0, 1, 0, 1, , );                                                         \
    PHASE(1, 1, 0, 1, 0, , );                                                         \
    PHASE(1, 1, 1, 0, 0, , );                                                         \
} while (0)

template<int KDIM, int EPI>
__launch_bounds__(512, 2)
__global__ void gemm256(const _Float16* __restrict__ A,
                        const _Float16* __restrict__ B,
                        void* __restrict__ Cout) {
    constexpr int NT = KDIM / 64;                 // 32 (gemm1) / 22 (gemm2): even, >= 4
    __shared__ __align__(16) _Float16 As[2][16384];   // [buf][256 rows * 64 halves]
    __shared__ __align__(16) _Float16 Bs[2][16384];

    const int t = threadIdx.x;
    const int wave = t >> 6, lane = t & 63;
    const int id = blockIdx.x;
    const int m0 = (id & 63) * 256;               // 64 m-panels exactly; m fastest (A L3-window)
    const int n_p = id >> 6;
    const int n0 = n_p * 256;
    const int wm = wave >> 2, wn = wave & 3;      // 2x4 wave grid; wave tile 128(M) x 64(N)
    const int q4 = lane >> 4, l15 = lane & 15;

    // staging: per-lane global source (pre-swizzled chunk), wave-uniform LDS dest
    const int srow = wave * 8 + (lane >> 3);
    const int schunk = (lane & 7) ^ (lane >> 3);
    const _Float16* ag = A + (size_t)(m0 + srow) * KDIM + schunk * 8;
    const _Float16* bg = B + (size_t)(n0 + srow) * KDIM + schunk * 8;
    const int ldst = wave * 512;                  // halves

    int aoff[4], boff[2];
#pragma unroll
    for (int i = 0; i < 4; ++i) {
        int rA = wm * 128 + i * 16 + l15;
        aoff[i] = rA * 64 + ((q4 ^ (rA & 7)) * 8);
    }
#pragma unroll
    for (int j = 0; j < 2; ++j) {
        int rB = wn * 64 + j * 16 + l15;
        boff[j] = rB * 64 + ((q4 ^ (rB & 7)) * 8);
    }

    floatx4 zero = {0.f, 0.f, 0.f, 0.f};
    floatx4 acc[8][4];
#pragma unroll
    for (int mi = 0; mi < 8; ++mi)
#pragma unroll
        for (int ni = 0; ni < 4; ++ni) acc[mi][ni] = zero;

    half8 af[4][2];        // current A quadrant frags (live across 2 phases)
    half8 bf[2][2][2];     // [nh][frag][kk] — both B halves kept live

    // prologue: B0(0),A0(0),A1(0),B1(0),B0(1),A0(1) = 12 in flight
    STAGE_B(0, 0, 0);
    STAGE_A(0, 0, 0);
    STAGE_A(0, 1, 0);
    STAGE_B(0, 1, 0);
    STAGE_B(1, 0, 1);
    STAGE_A(1, 0, 1);
    VM(8);                                        // drain B0(0),A0(0)
    __builtin_amdgcn_s_barrier();

    for (int tt = 0; tt < NT - 2; tt += 2) {
        TILE_FULL(0, tt);
        TILE_FULL(1, tt + 1);
    }
    TILE_PEN(NT - 2);
    TILE_LAST();

    if constexpr (EPI == 1) {
        // ni 0,1 = gate, ni 2,3 = up of the same h-columns
        _Float16* hout = (_Float16*)Cout;
        const int rbase = m0 + wm * 128 + q4 * 4;
        const int colbase = (n_p * 4 + wn) * 32 + l15;
#pragma unroll
        for (int mi = 0; mi < 8; ++mi)
#pragma unroll
            for (int nc = 0; nc < 2; ++nc)
#pragma unroll
                for (int r = 0; r < 4; ++r) {
                    int row = rbase + mi * 16 + r;
                    int col = colbase + nc * 16;
                    float g = acc[mi][nc][r];
                    float u = acc[mi][nc + 2][r];
                    float s = (g / (1.0f + __expf(-g))) * u;
                    hout[(size_t)row * I_DIM + col] = (_Float16)s;
                }
    } else {
        float* outp = (float*)Cout;
        const int rbase = m0 + wm * 128 + q4 * 4;
#pragma unroll
        for (int mi = 0; mi < 8; ++mi)
#pragma unroll
            for (int ni = 0; ni < 4; ++ni)
#pragma unroll
                for (int r = 0; r < 4; ++r) {
                    int row = rbase + mi * 16 + r;
                    int col = n0 + wn * 64 + ni * 16 + l15;
                    outp[(size_t)row * H_DIM + col] = acc[mi][ni][r];
                }
    }
}

extern "C" void kernel_launch(void* const* d_in, const int* in_sizes, int n_in,
                              void* d_out, int out_size, void* d_ws, size_t ws_size,
                              hipStream_t stream) {
    const float* x    = (const float*)d_in[0];
    const int* qw_g   = (const int*)d_in[1];
    const int* qz_g   = (const int*)d_in[2];
    const float* sc_g = (const float*)d_in[3];
    const int* qw_u   = (const int*)d_in[4];
    const int* qz_u   = (const int*)d_in[5];
    const float* sc_u = (const float*)d_in[6];
    const int* qw_d   = (const int*)d_in[7];
    const int* qz_d   = (const int*)d_in[8];
    const float* sc_d = (const float*)d_in[9];
    float* out = (float*)d_out;

    // ws (fp16): xh 64MiB | h 44MiB | B' 11MiB | Wd_t 5.5MiB
    char* ws = (char*)d_ws;
    _Float16* xh  = (_Float16*)ws;  ws += (size_t)T_DIM * H_DIM * sizeof(_Float16);
    _Float16* hh  = (_Float16*)ws;  ws += (size_t)T_DIM * I_DIM * sizeof(_Float16);
    _Float16* Bgu = (_Float16*)ws;  ws += (size_t)NB_DIM * H_DIM * sizeof(_Float16);
    _Float16* Wd  = (_Float16*)ws;  ws += (size_t)I_DIM * H_DIM * sizeof(_Float16);

    cvt_fp16_kernel<<<(T_DIM * H_DIM) / 2048, 256, 0, stream>>>(x, xh);
    dequant_kernel<<<dim3(I_DIM / 64, H_DIM / 32), 256, 0, stream>>>(qw_g, qz_g, sc_g, Bgu, H_DIM, I_DIM, 1, 0);
    dequant_kernel<<<dim3(I_DIM / 64, H_DIM / 32), 256, 0, stream>>>(qw_u, qz_u, sc_u, Bgu, H_DIM, I_DIM, 1, 32);
    dequant_kernel<<<dim3(H_DIM / 64, I_DIM / 32), 256, 0, stream>>>(qw_d, qz_d, sc_d, Wd, I_DIM, H_DIM, 0, 0);
    gemm256<H_DIM, 1><<<(T_DIM / 256) * (NB_DIM / 256), 512, 0, stream>>>(xh, Bgu, hh);
    gemm256<I_DIM, 0><<<(T_DIM / 256) * (H_DIM / 256), 512, 0, stream>>>(hh, Wd, out);
}